// Round 7
// baseline (56.689 us; speedup 1.0000x reference)
//
#include <hip/hip_runtime.h>

#define NQ 12
#define NL 5
#define TPB 64

// ---------- compile-time address algebra (GF(2)-linear) ----------
__host__ __device__ constexpr int sfx12_(int x) {
    x ^= x >> 1; x ^= x >> 2; x ^= x >> 4; x ^= x >> 8;
    return x & 0xFFF;
}
__host__ __device__ constexpr int par_(int x) {
    int y = x; y ^= y >> 8; y ^= y >> 4; y ^= y >> 2; y ^= y >> 1;
    return y & 1;
}
// amp i -> byte addr: g=i>>1 (11b), G = g ^ ((g>>5)&7), addr = G<<4 | (i&1)<<3.
// Linear over GF(2): amp_addr(a^b) = amp_addr(a)^amp_addr(b).
__host__ __device__ constexpr int amp_addr(int i) {
    const int g = i >> 1;
    const int G = g ^ ((g >> 5) & 7);
    return (G << 4) | ((i & 1) << 3);
}
// CNOT ring: new[i]=old[f(i)], f(j)=j^(j>>1)^((j&1)*0xC00); f^-1(i)=sfx12(i)^(par(i)<<11).
__host__ __device__ constexpr int fi_(int x) { return sfx12_(x) ^ (par_(x) << 11); }
__host__ __device__ constexpr int mpat(int m) { return amp_addr(m << 6); }      // pass-2 read
__host__ __device__ constexpr int spat(int m) { return amp_addr(fi_(m << 6)); } // scatter
__host__ __device__ constexpr int mh_(int m) { return (fi_(m << 6) >> 8) & 15; }// meas signs

// ---------- gate kernels ----------
__device__ __forceinline__ void gate_pair(float2 &a, float2 &c,
        const float2 u00, const float2 u01, const float2 u10, const float2 u11) {
    float2 n0, n1;
    n0.x = fmaf(u00.x, a.x, fmaf(-u00.y, a.y, fmaf(u01.x, c.x, -u01.y * c.y)));
    n0.y = fmaf(u00.x, a.y, fmaf( u00.y, a.x, fmaf(u01.x, c.y,  u01.y * c.x)));
    n1.x = fmaf(u10.x, a.x, fmaf(-u10.y, a.y, fmaf(u11.x, c.x, -u11.y * c.y)));
    n1.y = fmaf(u10.x, a.y, fmaf( u10.y, a.x, fmaf(u11.x, c.y,  u11.y * c.x)));
    a = n0; c = n1;
}
// gate on register-index bit K of the 64 in-register amplitudes
template <int K>
__device__ __forceinline__ void apply_gate(float2 (&v)[64], const float2* __restrict__ Uq) {
    const float2 u00 = Uq[0], u01 = Uq[1], u10 = Uq[2], u11 = Uq[3];
#pragma unroll
    for (int h = 0; h < 32; ++h) {
        const int m0 = ((h >> K) << (K + 1)) | (h & ((1 << K) - 1));
        gate_pair(v[m0], v[m0 | (1 << K)], u00, u01, u10, u11);
    }
    __builtin_amdgcn_sched_barrier(0);   // cap scheduler window -> bound VGPR pressure
}

extern "C" __global__ void __launch_bounds__(TPB)
qnet_kernel(const float* __restrict__ x, const float* __restrict__ iw,
            const float* __restrict__ th, const float* __restrict__ ow,
            float* __restrict__ out) {
    // One WAVE per batch element: whole 4096-amp state owned by 64 threads.
    // LDS in-order per wave => ZERO barriers in the entire kernel.
    __shared__ float2 st[4096];                      // 32 KB state, swizzled
    __shared__ __align__(16) float2 U[NL][NQ][4];    // gate matrices
    char* stb = (char*)st;

    const int b = blockIdx.x;
    const int tid = threadIdx.x;

    // --- precompute all 60 gate matrices U = M(b,c) @ Rx(a) (one wave: in-order vis) ---
    if (tid < NL * NQ) {
        const int l = tid / NQ, q = tid % NQ;
        const float xv = tanhf(x[b * NQ + q]);
        const float a = iw[l * NQ + q] * xv;
        const float bt = th[(l * NQ + q) * 2 + 0];
        const float ct = th[(l * NQ + q) * 2 + 1];
        float sa, ca; sincosf(0.5f * a, &sa, &ca);
        float sb, cb; sincosf(0.5f * bt, &sb, &cb);
        float sc, cc; sincosf(0.5f * ct, &sc, &cc);
        const float M00r = cc * cb, M00i = -sc * cb;
        const float M01r = -cc * sb, M01i = sc * sb;
        const float M10r = cc * sb, M10i = sc * sb;
        const float M11r = cc * cb, M11i = sc * cb;
        U[l][q][0] = make_float2(fmaf(M00r, ca,  sa * M01i), fmaf(M00i, ca, -sa * M01r));
        U[l][q][1] = make_float2(fmaf(ca, M01r,  sa * M00i), fmaf(ca, M01i, -sa * M00r));
        U[l][q][2] = make_float2(fmaf(M10r, ca,  sa * M11i), fmaf(M10i, ca, -sa * M11r));
        U[l][q][3] = make_float2(fmaf(ca, M11r,  sa * M10i), fmaf(ca, M11i, -sa * M10r));
    }

    // --- per-thread address bases ---
    const int baseA = amp_addr(tid << 6);       // pass-1: ^ (c<<4), c=0..31
    const int baseB = amp_addr(tid);            // pass-2 read: ^ mpat(m)
    const int pt = __popc(tid) & 1;
    const int baseS = amp_addr(fi_(tid));       // scatter: ^ spat(m)
    const int hT = pt << 3;                     // f^-1(t) bits 11..8

    float2 v[64];                               // 128 VGPRs of state
#pragma unroll 1
    for (int l = 0; l < NL; ++l) {
        // ---- pass 1: amp bits 0-5 (qubits 11..6), b128 gather ----
        if (l == 0) {
#pragma unroll
            for (int r = 0; r < 64; ++r) v[r] = make_float2(0.f, 0.f);
            if (tid == 0) v[0].x = 1.f;          // |0...0>
        } else {
#pragma unroll
            for (int c = 0; c < 32; ++c) {
                const float4 f = *(const float4*)(stb + (baseA ^ (c << 4)));
                v[2 * c]     = make_float2(f.x, f.y);
                v[2 * c + 1] = make_float2(f.z, f.w);
            }
        }
        apply_gate<0>(v, U[l][11]);
        apply_gate<1>(v, U[l][10]);
        apply_gate<2>(v, U[l][9]);
        apply_gate<3>(v, U[l][8]);
        apply_gate<4>(v, U[l][7]);
        apply_gate<5>(v, U[l][6]);
        // transpose write (b128); wave-in-order LDS, no sync needed
#pragma unroll
        for (int c = 0; c < 32; ++c)
            *(float4*)(stb + (baseA ^ (c << 4))) =
                make_float4(v[2 * c].x, v[2 * c].y, v[2 * c + 1].x, v[2 * c + 1].y);

        // ---- pass 2: amp bits 6-11 (qubits 5..0), b64 ----
#pragma unroll
        for (int m = 0; m < 64; ++m)
            v[m] = *(const float2*)(stb + (baseB ^ mpat(m)));
        apply_gate<0>(v, U[l][5]);
        apply_gate<1>(v, U[l][4]);
        apply_gate<2>(v, U[l][3]);
        apply_gate<3>(v, U[l][2]);
        apply_gate<4>(v, U[l][1]);
        apply_gate<5>(v, U[l][0]);
        if (l != NL - 1) {
            // CNOT-ring fused scatter: amp i stored at addr(f^-1(i))
#pragma unroll
            for (int m = 0; m < 64; ++m)
                *(float2*)(stb + (baseS ^ spat(m))) = v[m];
        }
    }

    // ---- layer-4: CNOT perm + measurement fused, straight from registers ----
    float z0 = 0.f, z1 = 0.f, z2 = 0.f, z3 = 0.f;
#pragma unroll
    for (int m = 0; m < 64; ++m) {
        const float pr = fmaf(v[m].x, v[m].x, v[m].y * v[m].y);
        const int h = mh_(m) ^ hT;   // bits 11..8 of f^-1((m<<6)|tid)
        z0 += (h & 8) ? -pr : pr;
        z1 += (h & 4) ? -pr : pr;
        z2 += (h & 2) ? -pr : pr;
        z3 += (h & 1) ? -pr : pr;
    }
#pragma unroll
    for (int off = 32; off > 0; off >>= 1) {
        z0 += __shfl_xor(z0, off);
        z1 += __shfl_xor(z1, off);
        z2 += __shfl_xor(z2, off);
        z3 += __shfl_xor(z3, off);
    }
    if (tid == 0) {
        const float4 o = make_float4(ow[0] * z0, ow[1] * z1, ow[2] * z2, ow[3] * z3);
        *(float4*)(out + b * 4) = o;
    }
}

extern "C" void kernel_launch(void* const* d_in, const int* in_sizes, int n_in,
                              void* d_out, int out_size, void* d_ws, size_t ws_size,
                              hipStream_t stream) {
    const float* x  = (const float*)d_in[0];
    const float* iw = (const float*)d_in[1];
    const float* th = (const float*)d_in[2];
    const float* ow = (const float*)d_in[3];
    float* out = (float*)d_out;
    const int batch = in_sizes[0] / NQ;
    hipLaunchKernelGGL(qnet_kernel, dim3(batch), dim3(TPB), 0, stream,
                       x, iw, th, ow, out);
}

// Round 8
// 49.175 us; speedup vs baseline: 1.1528x; 1.1528x over previous
//
#include <hip/hip_runtime.h>

#define NQ 12
#define NL 5
#define TPB 256

// ---------- compile-time address algebra (GF(2)-linear, R3-verified) ----------
__host__ __device__ constexpr int sfx12_(int x) {
    x ^= x >> 1; x ^= x >> 2; x ^= x >> 4; x ^= x >> 8;
    return x & 0xFFF;
}
// amp i lives at byte (G<<4)|((i&1)<<3), G = g ^ ((g>>3)&7), g = i>>1.  Linear in i.
__host__ __device__ constexpr int amp_addr(int i) {
    const int g = i >> 1;
    const int G = g ^ ((g >> 3) & 7);
    return (G << 4) | ((i & 1) << 3);
}
// CNOT ring: new[i]=old[f(i)], f(j)=j^(j>>1)^((j&1)*0xC00); f^-1(i)=sfx12(i)^(par(i)<<11).
__host__ __device__ constexpr int scat_c(int m) {          // scatter m-part address
    const int s = sfx12_(m << 8);
    return amp_addr(s ^ ((s & 1) << 11));
}
__host__ __device__ constexpr int bpat(int m) { return amp_addr(m << 4); }   // pass-B m-part

// ---------- packed-FP32 complex arithmetic (2 VOP3P per complex mul-add) ----------
// Register convention: float2 z = (re, im) in an even-aligned VGPR pair (lo=re, hi=im).
// un = (-u.im, u.im).
// cmul_pk: d = u (*) z        (complex multiply)
//   instr1 (v_pk_mul_f32, op_sel:[0,1] op_sel_hi:[1,0]):
//       t.lo = un.lo * z.hi = -ui*zy          t.hi = un.hi * z.lo = ui*zx
//   instr2 (v_pk_fma_f32, op_sel:[0,0,0] op_sel_hi:[0,1,1]):  (src0 broadcasts u.lo=ur)
//       d.lo = ur*zx + t.lo = ur*zx - ui*zy   d.hi = ur*zy + t.hi = ur*zy + ui*zx
__device__ __forceinline__ float2 cmul_pk(float2 u, float2 un, float2 z) {
    float2 d, t;
    asm("v_pk_mul_f32 %1, %3, %4 op_sel:[0,1] op_sel_hi:[1,0]\n\t"
        "v_pk_fma_f32 %0, %2, %4, %1 op_sel:[0,0,0] op_sel_hi:[0,1,1]"
        : "=v"(d), "=&v"(t)
        : "v"(u), "v"(un), "v"(z));
    return d;
}
// cfma_pk: d = u (*) z + c
//   instr1 (v_pk_fma_f32, op_sel:[0,1,0] op_sel_hi:[1,0,1]):
//       t.lo = -ui*zy + c.lo                  t.hi = ui*zx + c.hi
//   instr2: as above.
__device__ __forceinline__ float2 cfma_pk(float2 u, float2 un, float2 z, float2 c) {
    float2 d, t;
    asm("v_pk_fma_f32 %1, %3, %4, %5 op_sel:[0,1,0] op_sel_hi:[1,0,1]\n\t"
        "v_pk_fma_f32 %0, %2, %4, %1 op_sel:[0,0,0] op_sel_hi:[0,1,1]"
        : "=v"(d), "=&v"(t)
        : "v"(u), "v"(un), "v"(z), "v"(c));
    return d;
}

// gate on register-index bit K: n0 = u00(*)a + u01(*)c ; n1 = u10(*)a + u11(*)c
template <int K>
__device__ __forceinline__ void apply_gate(float2 (&v)[16], const float2* __restrict__ Uq) {
    const float2 u00 = Uq[0], u01 = Uq[1], u10 = Uq[2], u11 = Uq[3];
    const float2 u00n = make_float2(-u00.y, u00.y);
    const float2 u01n = make_float2(-u01.y, u01.y);
    const float2 u10n = make_float2(-u10.y, u10.y);
    const float2 u11n = make_float2(-u11.y, u11.y);
#pragma unroll
    for (int h = 0; h < 8; ++h) {
        const int m0 = ((h >> K) << (K + 1)) | (h & ((1 << K) - 1));
        const int m1 = m0 | (1 << K);
        const float2 a = v[m0], c = v[m1];
        const float2 n0 = cfma_pk(u00, u00n, a, cmul_pk(u01, u01n, c));
        const float2 n1 = cfma_pk(u10, u10n, a, cmul_pk(u11, u11n, c));
        v[m0] = n0;
        v[m1] = n1;
    }
}

extern "C" __global__ void __launch_bounds__(TPB)
qnet_kernel(const float* __restrict__ x, const float* __restrict__ iw,
            const float* __restrict__ th, const float* __restrict__ ow,
            float* __restrict__ out) {
    __shared__ float2 st[4096];                      // 32 KB state, swizzled
    __shared__ __align__(16) float2 U[NL][NQ][4];    // gate matrices
    __shared__ float wz[4][4];
    char* stb = (char*)st;

    const int b = blockIdx.x;
    const int tid = threadIdx.x;
    const int w = tid >> 6;

    // --- precompute all 60 gate matrices U = M(b,c) @ Rx(a) ---
    if (tid < NL * NQ) {
        const int l = tid / NQ, q = tid % NQ;
        const float xv = tanhf(x[b * NQ + q]);
        const float a = iw[l * NQ + q] * xv;
        const float bt = th[(l * NQ + q) * 2 + 0];
        const float ct = th[(l * NQ + q) * 2 + 1];
        float sa, ca; sincosf(0.5f * a, &sa, &ca);
        float sb, cb; sincosf(0.5f * bt, &sb, &cb);
        float sc, cc; sincosf(0.5f * ct, &sc, &cc);
        const float M00r = cc * cb, M00i = -sc * cb;
        const float M01r = -cc * sb, M01i = sc * sb;
        const float M10r = cc * sb, M10i = sc * sb;
        const float M11r = cc * cb, M11i = sc * cb;
        U[l][q][0] = make_float2(fmaf(M00r, ca,  sa * M01i), fmaf(M00i, ca, -sa * M01r));
        U[l][q][1] = make_float2(fmaf(ca, M01r,  sa * M00i), fmaf(ca, M01i, -sa * M00r));
        U[l][q][2] = make_float2(fmaf(M10r, ca,  sa * M11i), fmaf(M10i, ca, -sa * M11r));
        U[l][q][3] = make_float2(fmaf(ca, M11r,  sa * M11i * 0.f + sa * M10i),
                                 fmaf(ca, M11i, -sa * M10r));
    }
    // NOTE: the line above must match R3 exactly; rewrite it cleanly:
    if (tid < NL * NQ) {
        const int l = tid / NQ, q = tid % NQ;
        const float xv = tanhf(x[b * NQ + q]);
        const float a = iw[l * NQ + q] * xv;
        const float bt = th[(l * NQ + q) * 2 + 0];
        const float ct = th[(l * NQ + q) * 2 + 1];
        float sa, ca; sincosf(0.5f * a, &sa, &ca);
        float sb, cb; sincosf(0.5f * bt, &sb, &cb);
        float sc, cc; sincosf(0.5f * ct, &sc, &cc);
        const float M00r = cc * cb, M00i = -sc * cb;
        const float M01r = -cc * sb, M01i = sc * sb;
        const float M10r = cc * sb, M10i = sc * sb;
        const float M11r = cc * cb, M11i = sc * cb;
        U[l][q][0] = make_float2(fmaf(M00r, ca,  sa * M01i), fmaf(M00i, ca, -sa * M01r));
        U[l][q][1] = make_float2(fmaf(ca, M01r,  sa * M00i), fmaf(ca, M01i, -sa * M00r));
        U[l][q][2] = make_float2(fmaf(M10r, ca,  sa * M11i), fmaf(M10i, ca, -sa * M11r));
        U[l][q][3] = make_float2(fmaf(ca, M11r,  sa * M10i), fmaf(ca, M11i, -sa * M10r));
    }

    // --- per-thread address bases (1 XOR w/ const per LDS access in the loop) ---
    const int baseA = amp_addr(tid << 4);                              // ^ (c<<4)
    const int baseB = amp_addr(((tid >> 4) << 8) | (tid & 15));        // ^ bpat(m)
    const int baseC = amp_addr(tid);                                   // + (m<<11)
    const int pt = __popc(tid) & 1;
    const int baseS = amp_addr(sfx12_(tid) ^ (pt << 11));              // ^ scat_c(m)

    __syncthreads();   // U visible

    float2 v[16];
#pragma unroll
    for (int l = 0; l < NL; ++l) {
        // ---- pass A: amp bits 0-3 (qubits 11..8) ----
        if (l == 0) {
#pragma unroll
            for (int r = 0; r < 16; ++r) v[r] = make_float2(0.f, 0.f);
            if (tid == 0) v[0].x = 1.f;          // |0...0>
        } else {
#pragma unroll
            for (int c = 0; c < 8; ++c) {
                const float4 f = *(const float4*)(stb + (baseA ^ (c << 4)));
                v[2 * c]     = make_float2(f.x, f.y);
                v[2 * c + 1] = make_float2(f.z, f.w);
            }
        }
        apply_gate<0>(v, U[l][11]);
        apply_gate<1>(v, U[l][10]);
        apply_gate<2>(v, U[l][9]);
        apply_gate<3>(v, U[l][8]);
#pragma unroll
        for (int c = 0; c < 8; ++c)
            *(float4*)(stb + (baseA ^ (c << 4))) =
                make_float4(v[2 * c].x, v[2 * c].y, v[2 * c + 1].x, v[2 * c + 1].y);
        __syncthreads();

        // ---- pass B: amp bits 4-7 (qubits 7..4) ----
#pragma unroll
        for (int m = 0; m < 16; ++m)
            v[m] = *(const float2*)(stb + (baseB ^ bpat(m)));
        apply_gate<0>(v, U[l][7]);
        apply_gate<1>(v, U[l][6]);
        apply_gate<2>(v, U[l][5]);
        apply_gate<3>(v, U[l][4]);
#pragma unroll
        for (int m = 0; m < 16; ++m)
            *(float2*)(stb + (baseB ^ bpat(m))) = v[m];
        __syncthreads();

        // ---- pass C: amp bits 8-11 (qubits 3..0); static-offset reads ----
#pragma unroll
        for (int m = 0; m < 16; ++m)
            v[m] = *(const float2*)(stb + baseC + (m << 11));
        apply_gate<0>(v, U[l][3]);
        apply_gate<1>(v, U[l][2]);
        apply_gate<2>(v, U[l][1]);
        apply_gate<3>(v, U[l][0]);
        __syncthreads();   // all pass-C reads consumed before scatter overwrites
        // CNOT-ring fused scatter: amp i -> address of f^-1(i)
#pragma unroll
        for (int m = 0; m < 16; ++m)
            *(float2*)(stb + (baseS ^ scat_c(m))) = v[m];
        __syncthreads();   // scatter visible to next pass A / measurement
    }

    // --- measurement: state canonical (perm already applied); own b128 chunks ---
    float ps = 0.f;
#pragma unroll
    for (int c = 0; c < 8; ++c) {
        const float4 f = *(const float4*)(stb + (baseA ^ (c << 4)));
        ps = fmaf(f.x, f.x, fmaf(f.y, f.y, fmaf(f.z, f.z, fmaf(f.w, f.w, ps))));
    }
    // Z on qubits 0..3 = amp bits 11..8 = tid bits 7..4 (constant per thread)
    float s0 = (tid & 128) ? -ps : ps;
    float s1 = (tid & 64) ? -ps : ps;
    float s2 = (tid & 32) ? -ps : ps;
    float s3 = (tid & 16) ? -ps : ps;
#pragma unroll
    for (int off = 32; off > 0; off >>= 1) {
        s0 += __shfl_xor(s0, off);
        s1 += __shfl_xor(s1, off);
        s2 += __shfl_xor(s2, off);
        s3 += __shfl_xor(s3, off);
    }
    if ((tid & 63) == 0) {
        wz[w][0] = s0; wz[w][1] = s1; wz[w][2] = s2; wz[w][3] = s3;
    }
    __syncthreads();
    if (tid < 4) {
        const float z = wz[0][tid] + wz[1][tid] + wz[2][tid] + wz[3][tid];
        out[b * 4 + tid] = ow[tid] * z;
    }
}

extern "C" void kernel_launch(void* const* d_in, const int* in_sizes, int n_in,
                              void* d_out, int out_size, void* d_ws, size_t ws_size,
                              hipStream_t stream) {
    const float* x  = (const float*)d_in[0];
    const float* iw = (const float*)d_in[1];
    const float* th = (const float*)d_in[2];
    const float* ow = (const float*)d_in[3];
    float* out = (float*)d_out;
    const int batch = in_sizes[0] / NQ;
    hipLaunchKernelGGL(qnet_kernel, dim3(batch), dim3(TPB), 0, stream,
                       x, iw, th, ow, out);
}

// Round 9
// 48.821 us; speedup vs baseline: 1.1611x; 1.0072x over previous
//
#include <hip/hip_runtime.h>

#define NQ 12
#define NL 5
#define TPB 256
#define NGATES (NL * NQ)   // 60 gates per batch element

// ---------- compile-time address algebra (GF(2)-linear, R3-verified) ----------
__host__ __device__ constexpr int sfx12_(int x) {
    x ^= x >> 1; x ^= x >> 2; x ^= x >> 4; x ^= x >> 8;
    return x & 0xFFF;
}
__host__ __device__ constexpr int par_(int x) {
    int y = x; y ^= y >> 8; y ^= y >> 4; y ^= y >> 2; y ^= y >> 1;
    return y & 1;
}
// amp i lives at byte (G<<4)|((i&1)<<3), G = g ^ ((g>>3)&7), g = i>>1.  Linear in i.
__host__ __device__ constexpr int amp_addr(int i) {
    const int g = i >> 1;
    const int G = g ^ ((g >> 3) & 7);
    return (G << 4) | ((i & 1) << 3);
}
// CNOT ring: new[i]=old[f(i)], f(j)=j^(j>>1)^((j&1)*0xC00); f^-1(i)=sfx12(i)^(par(i)<<11).
__host__ __device__ constexpr int scat_c(int m) {          // scatter m-part address
    const int s = sfx12_(m << 8);
    return amp_addr(s ^ ((s & 1) << 11));
}
__host__ __device__ constexpr int bpat(int m) { return amp_addr(m << 4); }   // pass-B m-part
__host__ __device__ constexpr int meas_h(int m) {          // bits 11..8 of f^-1(m<<8)
    const int d = sfx12_(m << 8) ^ (par_(m) << 11);
    return (d >> 8) & 15;
}

// ---------- gate kernels (coefficients come in as block-uniform scalars -> SGPRs) ----------
__device__ __forceinline__ void gate_pair(float2 &a, float2 &c,
        const float2 u00, const float2 u01, const float2 u10, const float2 u11) {
    float2 n0, n1;
    n0.x = fmaf(u00.x, a.x, fmaf(-u00.y, a.y, fmaf(u01.x, c.x, -u01.y * c.y)));
    n0.y = fmaf(u00.x, a.y, fmaf( u00.y, a.x, fmaf(u01.x, c.y,  u01.y * c.x)));
    n1.x = fmaf(u10.x, a.x, fmaf(-u10.y, a.y, fmaf(u11.x, c.x, -u11.y * c.y)));
    n1.y = fmaf(u10.x, a.y, fmaf( u10.y, a.x, fmaf(u11.x, c.y,  u11.y * c.x)));
    a = n0; c = n1;
}
// gate on register-index bit K; g = uniform pointer into the global gate table
template <int K>
__device__ __forceinline__ void apply_gate(float2 (&v)[16], const float* __restrict__ g) {
    const float2 u00 = make_float2(g[0], g[1]);
    const float2 u01 = make_float2(g[2], g[3]);
    const float2 u10 = make_float2(g[4], g[5]);
    const float2 u11 = make_float2(g[6], g[7]);
#pragma unroll
    for (int h = 0; h < 8; ++h) {
        const int m0 = ((h >> K) << (K + 1)) | (h & ((1 << K) - 1));
        gate_pair(v[m0], v[m0 | (1 << K)], u00, u01, u10, u11);
    }
}

// ---------- kernel 1: precompute all gate matrices U = M(b,c) @ Rx(a) ----------
extern "C" __global__ void __launch_bounds__(256)
prep_gates(const float* __restrict__ x, const float* __restrict__ iw,
           const float* __restrict__ th, float* __restrict__ Ug, int total) {
    const int idx = blockIdx.x * 256 + threadIdx.x;
    if (idx >= total) return;
    const int b = idx / NGATES;
    const int r = idx % NGATES;
    const int l = r / NQ, q = r % NQ;
    const float xv = tanhf(x[b * NQ + q]);
    const float a = iw[l * NQ + q] * xv;
    const float bt = th[(l * NQ + q) * 2 + 0];
    const float ct = th[(l * NQ + q) * 2 + 1];
    float sa, ca; sincosf(0.5f * a, &sa, &ca);
    float sb, cb; sincosf(0.5f * bt, &sb, &cb);
    float sc, cc; sincosf(0.5f * ct, &sc, &cc);
    const float M00r = cc * cb, M00i = -sc * cb;
    const float M01r = -cc * sb, M01i = sc * sb;
    const float M10r = cc * sb, M10i = sc * sb;
    const float M11r = cc * cb, M11i = sc * cb;
    float4 lo, hi;
    lo.x = fmaf(M00r, ca,  sa * M01i); lo.y = fmaf(M00i, ca, -sa * M01r);
    lo.z = fmaf(ca, M01r,  sa * M00i); lo.w = fmaf(ca, M01i, -sa * M00r);
    hi.x = fmaf(M10r, ca,  sa * M11i); hi.y = fmaf(M10i, ca, -sa * M11r);
    hi.z = fmaf(ca, M11r,  sa * M10i); hi.w = fmaf(ca, M11i, -sa * M10r);
    *(float4*)(Ug + idx * 8)     = lo;
    *(float4*)(Ug + idx * 8 + 4) = hi;
}

// ---------- kernel 2: state evolution (one block per batch element) ----------
extern "C" __global__ void __launch_bounds__(TPB)
qnet_kernel(const float* __restrict__ Ug, const float* __restrict__ ow,
            float* __restrict__ out) {
    __shared__ float2 st[4096];          // 32 KB state, swizzled slots
    __shared__ float wz[4][4];
    char* stb = (char*)st;

    const int b = blockIdx.x;
    const int tid = threadIdx.x;
    const int w = tid >> 6;
    // uniform per-block gate table: gate (l,q) at Ub + (l*12+q)*8  -> s_load'd
    const float* __restrict__ Ub = Ug + b * (NGATES * 8);

    // --- per-thread address bases (1 XOR w/ const per LDS access in the loop) ---
    const int baseA = amp_addr(tid << 4);                              // ^ (c<<4)
    const int baseB = amp_addr(((tid >> 4) << 8) | (tid & 15));        // ^ bpat(m)
    const int baseC = amp_addr(tid);                                   // + (m<<11)
    const int pt = __popc(tid) & 1;
    const int baseS = amp_addr(sfx12_(tid) ^ (pt << 11));              // ^ scat_c(m)
    const int hT = pt << 3;                                            // f^-1 t-part hi nibble

    float2 v[16];
#pragma unroll
    for (int l = 0; l < NL; ++l) {
        const float* __restrict__ Ul = Ub + l * (NQ * 8);
        // ---- pass A: amp bits 0-3 (qubits 11..8) ----
        if (l == 0) {
#pragma unroll
            for (int r = 0; r < 16; ++r) v[r] = make_float2(0.f, 0.f);
            if (tid == 0) v[0].x = 1.f;          // |0...0>
        } else {
#pragma unroll
            for (int c = 0; c < 8; ++c) {
                const float4 f = *(const float4*)(stb + (baseA ^ (c << 4)));
                v[2 * c]     = make_float2(f.x, f.y);
                v[2 * c + 1] = make_float2(f.z, f.w);
            }
        }
        apply_gate<0>(v, Ul + 11 * 8);
        apply_gate<1>(v, Ul + 10 * 8);
        apply_gate<2>(v, Ul + 9 * 8);
        apply_gate<3>(v, Ul + 8 * 8);
#pragma unroll
        for (int c = 0; c < 8; ++c)
            *(float4*)(stb + (baseA ^ (c << 4))) =
                make_float4(v[2 * c].x, v[2 * c].y, v[2 * c + 1].x, v[2 * c + 1].y);
        __syncthreads();

        // ---- pass B: amp bits 4-7 (qubits 7..4) ----
#pragma unroll
        for (int m = 0; m < 16; ++m)
            v[m] = *(const float2*)(stb + (baseB ^ bpat(m)));
        apply_gate<0>(v, Ul + 7 * 8);
        apply_gate<1>(v, Ul + 6 * 8);
        apply_gate<2>(v, Ul + 5 * 8);
        apply_gate<3>(v, Ul + 4 * 8);
#pragma unroll
        for (int m = 0; m < 16; ++m)
            *(float2*)(stb + (baseB ^ bpat(m))) = v[m];
        __syncthreads();

        // ---- pass C: amp bits 8-11 (qubits 3..0); static-offset reads ----
#pragma unroll
        for (int m = 0; m < 16; ++m)
            v[m] = *(const float2*)(stb + baseC + (m << 11));
        apply_gate<0>(v, Ul + 3 * 8);
        apply_gate<1>(v, Ul + 2 * 8);
        apply_gate<2>(v, Ul + 1 * 8);
        apply_gate<3>(v, Ul + 0 * 8);

        if (l != NL - 1) {
            __syncthreads();   // all pass-C reads consumed before scatter overwrites
            // CNOT-ring fused scatter: amp i -> address of f^-1(i)
#pragma unroll
            for (int m = 0; m < 16; ++m)
                *(float2*)(stb + (baseS ^ scat_c(m))) = v[m];
            __syncthreads();   // scatter visible to next layer's pass A
        }
    }

    // ---- layer-4: CNOT perm + measurement fused, straight from registers ----
    // (verified in R5/R6: same absmax as LDS path)
    float z0 = 0.f, z1 = 0.f, z2 = 0.f, z3 = 0.f;
#pragma unroll
    for (int m = 0; m < 16; ++m) {
        const float pr = fmaf(v[m].x, v[m].x, v[m].y * v[m].y);
        const int h = meas_h(m) ^ hT;   // bits 11..8 of f^-1((m<<8)|tid)
        z0 += (h & 8) ? -pr : pr;
        z1 += (h & 4) ? -pr : pr;
        z2 += (h & 2) ? -pr : pr;
        z3 += (h & 1) ? -pr : pr;
    }
#pragma unroll
    for (int off = 32; off > 0; off >>= 1) {
        z0 += __shfl_xor(z0, off);
        z1 += __shfl_xor(z1, off);
        z2 += __shfl_xor(z2, off);
        z3 += __shfl_xor(z3, off);
    }
    if ((tid & 63) == 0) {
        wz[w][0] = z0; wz[w][1] = z1; wz[w][2] = z2; wz[w][3] = z3;
    }
    __syncthreads();
    if (tid < 4) {
        const float z = wz[0][tid] + wz[1][tid] + wz[2][tid] + wz[3][tid];
        out[b * 4 + tid] = ow[tid] * z;
    }
}

extern "C" void kernel_launch(void* const* d_in, const int* in_sizes, int n_in,
                              void* d_out, int out_size, void* d_ws, size_t ws_size,
                              hipStream_t stream) {
    const float* x  = (const float*)d_in[0];
    const float* iw = (const float*)d_in[1];
    const float* th = (const float*)d_in[2];
    const float* ow = (const float*)d_in[3];
    float* out = (float*)d_out;
    const int batch = in_sizes[0] / NQ;
    float* Ug = (float*)d_ws;            // batch*60*8 floats = ~1.9 MB (< ws_size)
    const int total = batch * NGATES;
    hipLaunchKernelGGL(prep_gates, dim3((total + 255) / 256), dim3(256), 0, stream,
                       x, iw, th, Ug, total);
    hipLaunchKernelGGL(qnet_kernel, dim3(batch), dim3(TPB), 0, stream,
                       Ug, ow, out);
}

// Round 10
// 42.006 us; speedup vs baseline: 1.3495x; 1.1622x over previous
//
#include <hip/hip_runtime.h>

#define NQ 12
#define NL 5
#define TPB 256

// ---------- compile-time address algebra (GF(2)-linear, R3-verified) ----------
__host__ __device__ constexpr int sfx12_(int x) {
    x ^= x >> 1; x ^= x >> 2; x ^= x >> 4; x ^= x >> 8;
    return x & 0xFFF;
}
// amp i lives at byte (G<<4)|((i&1)<<3), G = g ^ ((g>>3)&7), g = i>>1.  Linear in i.
__host__ __device__ constexpr int amp_addr(int i) {
    const int g = i >> 1;
    const int G = g ^ ((g >> 3) & 7);
    return (G << 4) | ((i & 1) << 3);
}
// CNOT ring: new[i]=old[f(i)], f(j)=j^(j>>1)^((j&1)*0xC00); f^-1(i)=sfx12(i)^(par(i)<<11).
__host__ __device__ constexpr int scat_c(int m) {          // scatter m-part address
    const int s = sfx12_(m << 8);
    return amp_addr(s ^ ((s & 1) << 11));
}
__host__ __device__ constexpr int bpat(int m) { return amp_addr(m << 4); }   // pass-B m-part

// ---------- gate kernels ----------
__device__ __forceinline__ float2 cmul(float2 a, float2 b) {
    return make_float2(fmaf(a.x, b.x, -a.y * b.y), fmaf(a.x, b.y, a.y * b.x));
}
__device__ __forceinline__ void gate_pair(float2 &a, float2 &c,
        const float2 u00, const float2 u01, const float2 u10, const float2 u11) {
    float2 n0, n1;
    n0.x = fmaf(u00.x, a.x, fmaf(-u00.y, a.y, fmaf(u01.x, c.x, -u01.y * c.y)));
    n0.y = fmaf(u00.x, a.y, fmaf( u00.y, a.x, fmaf(u01.x, c.y,  u01.y * c.x)));
    n1.x = fmaf(u10.x, a.x, fmaf(-u10.y, a.y, fmaf(u11.x, c.x, -u11.y * c.y)));
    n1.y = fmaf(u10.x, a.y, fmaf( u10.y, a.x, fmaf(u11.x, c.y,  u11.y * c.x)));
    a = n0; c = n1;
}
template <int K>
__device__ __forceinline__ void apply_gate(float2 (&v)[16], const float2* __restrict__ Uq) {
    const float2 u00 = Uq[0], u01 = Uq[1], u10 = Uq[2], u11 = Uq[3];
#pragma unroll
    for (int h = 0; h < 8; ++h) {
        const int m0 = ((h >> K) << (K + 1)) | (h & ((1 << K) - 1));
        gate_pair(v[m0], v[m0 | (1 << K)], u00, u01, u10, u11);
    }
}

extern "C" __global__ void __launch_bounds__(TPB)
qnet_kernel(const float* __restrict__ x, const float* __restrict__ iw,
            const float* __restrict__ th, const float* __restrict__ ow,
            float* __restrict__ out) {
    __shared__ float2 st[4096];                      // 32 KB state, swizzled
    __shared__ __align__(16) float2 U[NL][NQ][4];    // gate matrices
    __shared__ float wz[4][4];
    char* stb = (char*)st;

    const int b = blockIdx.x;
    const int tid = threadIdx.x;
    const int w = tid >> 6;

    // --- precompute all 60 gate matrices U = M(b,c) @ Rx(a) ---
    if (tid < NL * NQ) {
        const int l = tid / NQ, q = tid % NQ;
        const float xv = tanhf(x[b * NQ + q]);
        const float a = iw[l * NQ + q] * xv;
        const float bt = th[(l * NQ + q) * 2 + 0];
        const float ct = th[(l * NQ + q) * 2 + 1];
        float sa, ca; sincosf(0.5f * a, &sa, &ca);
        float sb, cb; sincosf(0.5f * bt, &sb, &cb);
        float sc, cc; sincosf(0.5f * ct, &sc, &cc);
        const float M00r = cc * cb, M00i = -sc * cb;
        const float M01r = -cc * sb, M01i = sc * sb;
        const float M10r = cc * sb, M10i = sc * sb;
        const float M11r = cc * cb, M11i = sc * cb;
        U[l][q][0] = make_float2(fmaf(M00r, ca,  sa * M01i), fmaf(M00i, ca, -sa * M01r));
        U[l][q][1] = make_float2(fmaf(ca, M01r,  sa * M00i), fmaf(ca, M01i, -sa * M00r));
        U[l][q][2] = make_float2(fmaf(M10r, ca,  sa * M11i), fmaf(M10i, ca, -sa * M11r));
        U[l][q][3] = make_float2(fmaf(ca, M11r,  sa * M10i), fmaf(ca, M11i, -sa * M10r));
    }

    // --- per-thread address bases (1 XOR w/ const per LDS access in the loop) ---
    const int baseA = amp_addr(tid << 4);                              // ^ (c<<4)
    const int baseB = amp_addr(((tid >> 4) << 8) | (tid & 15));        // ^ bpat(m)
    const int baseC = amp_addr(tid);                                   // + (m<<11)
    const int pt = __popc(tid) & 1;
    const int baseS = amp_addr(sfx12_(tid) ^ (pt << 11));              // ^ scat_c(m)

    __syncthreads();   // U visible

    // ---- fused layer 0 (|0..0> is 1-hot): v[r] = psi1[(tid<<4)|r] in closed form ----
    // psi_after_gates(i) = prod_k c_k[bit_k(i)], c_k[bit] = column-0 of gate on qubit 11-k.
    // psi1(i) = psi_after_gates(f(i));  bits of j=f((t<<4)|r):
    //   j0=r0^r1 j1=r1^r2 j2=r2^r3 j3=r3^t0 j4=t0^t1 ... j9=t5^t6 j10=t6^t7^r0 j11=t7^r0
    float2 v[16];
    {
        const int t0 = tid & 1, t1 = (tid >> 1) & 1, t2 = (tid >> 2) & 1, t3 = (tid >> 3) & 1;
        const int t4 = (tid >> 4) & 1, t5 = (tid >> 5) & 1, t6 = (tid >> 6) & 1, t7 = (tid >> 7) & 1;
        // c_k[bit] = U[0][11-k][bit?2:0]
        #define C0(k, bit) (U[0][11 - (k)][(bit) ? 2 : 0])
        float2 Pm = cmul(C0(4, t0 ^ t1), C0(5, t1 ^ t2));
        Pm = cmul(Pm, C0(6, t2 ^ t3));
        Pm = cmul(Pm, C0(7, t3 ^ t4));
        Pm = cmul(Pm, C0(8, t4 ^ t5));
        Pm = cmul(Pm, C0(9, t5 ^ t6));
        float2 P3[2];                       // index r3
        P3[0] = cmul(Pm, C0(3, t0));
        P3[1] = cmul(Pm, C0(3, 1 ^ t0));
        float2 H[2];                        // index r0
        H[0] = cmul(C0(10, t6 ^ t7), C0(11, t7));
        H[1] = cmul(C0(10, t6 ^ t7 ^ 1), C0(11, t7 ^ 1));
        float2 PH[2][2];                    // [r0][r3]
        PH[0][0] = cmul(H[0], P3[0]); PH[0][1] = cmul(H[0], P3[1]);
        PH[1][0] = cmul(H[1], P3[0]); PH[1][1] = cmul(H[1], P3[1]);
        float2 T01[2][2];                   // [j0][j1]
        T01[0][0] = cmul(C0(0, 0), C0(1, 0)); T01[0][1] = cmul(C0(0, 0), C0(1, 1));
        T01[1][0] = cmul(C0(0, 1), C0(1, 0)); T01[1][1] = cmul(C0(0, 1), C0(1, 1));
        float2 L8[8];                       // [j0 | j1<<1 | j2<<2]
#pragma unroll
        for (int jj = 0; jj < 8; ++jj)
            L8[jj] = cmul(T01[jj & 1][(jj >> 1) & 1], C0(2, (jj >> 2) & 1));
        #undef C0
#pragma unroll
        for (int r = 0; r < 16; ++r) {
            const int r0 = r & 1, r1 = (r >> 1) & 1, r2 = (r >> 2) & 1, r3 = (r >> 3) & 1;
            v[r] = cmul(L8[(r0 ^ r1) | ((r1 ^ r2) << 1) | ((r2 ^ r3) << 2)], PH[r0][r3]);
        }
    }

#pragma unroll
    for (int l = 1; l < NL; ++l) {
        // ---- pass A: amp bits 0-3 (qubits 11..8) ----
        if (l > 1) {
#pragma unroll
            for (int c = 0; c < 8; ++c) {
                const float4 f = *(const float4*)(stb + (baseA ^ (c << 4)));
                v[2 * c]     = make_float2(f.x, f.y);
                v[2 * c + 1] = make_float2(f.z, f.w);
            }
        }
        apply_gate<0>(v, U[l][11]);
        apply_gate<1>(v, U[l][10]);
        apply_gate<2>(v, U[l][9]);
        apply_gate<3>(v, U[l][8]);
#pragma unroll
        for (int c = 0; c < 8; ++c)
            *(float4*)(stb + (baseA ^ (c << 4))) =
                make_float4(v[2 * c].x, v[2 * c].y, v[2 * c + 1].x, v[2 * c + 1].y);
        __syncthreads();

        // ---- pass B: amp bits 4-7 (qubits 7..4) ----
#pragma unroll
        for (int m = 0; m < 16; ++m)
            v[m] = *(const float2*)(stb + (baseB ^ bpat(m)));
        apply_gate<0>(v, U[l][7]);
        apply_gate<1>(v, U[l][6]);
        apply_gate<2>(v, U[l][5]);
        apply_gate<3>(v, U[l][4]);
#pragma unroll
        for (int m = 0; m < 16; ++m)
            *(float2*)(stb + (baseB ^ bpat(m))) = v[m];
        __syncthreads();

        // ---- pass C: amp bits 8-11 (qubits 3..0); static-offset reads ----
#pragma unroll
        for (int m = 0; m < 16; ++m)
            v[m] = *(const float2*)(stb + baseC + (m << 11));
        apply_gate<0>(v, U[l][3]);
        apply_gate<1>(v, U[l][2]);
        apply_gate<2>(v, U[l][1]);
        apply_gate<3>(v, U[l][0]);
        __syncthreads();   // all pass-C reads consumed before scatter overwrites
        // CNOT-ring fused scatter: amp i -> address of f^-1(i)
#pragma unroll
        for (int m = 0; m < 16; ++m)
            *(float2*)(stb + (baseS ^ scat_c(m))) = v[m];
        __syncthreads();   // scatter visible to next pass A / measurement
    }

    // --- measurement: state canonical (perm already applied); own b128 chunks ---
    float ps = 0.f;
#pragma unroll
    for (int c = 0; c < 8; ++c) {
        const float4 f = *(const float4*)(stb + (baseA ^ (c << 4)));
        ps = fmaf(f.x, f.x, fmaf(f.y, f.y, fmaf(f.z, f.z, fmaf(f.w, f.w, ps))));
    }
    // Z on qubits 0..3 = amp bits 11..8 = tid bits 7..4 (constant per thread)
    float s0 = (tid & 128) ? -ps : ps;
    float s1 = (tid & 64) ? -ps : ps;
    float s2 = (tid & 32) ? -ps : ps;
    float s3 = (tid & 16) ? -ps : ps;
#pragma unroll
    for (int off = 32; off > 0; off >>= 1) {
        s0 += __shfl_xor(s0, off);
        s1 += __shfl_xor(s1, off);
        s2 += __shfl_xor(s2, off);
        s3 += __shfl_xor(s3, off);
    }
    if ((tid & 63) == 0) {
        wz[w][0] = s0; wz[w][1] = s1; wz[w][2] = s2; wz[w][3] = s3;
    }
    __syncthreads();
    if (tid < 4) {
        const float z = wz[0][tid] + wz[1][tid] + wz[2][tid] + wz[3][tid];
        out[b * 4 + tid] = ow[tid] * z;
    }
}

extern "C" void kernel_launch(void* const* d_in, const int* in_sizes, int n_in,
                              void* d_out, int out_size, void* d_ws, size_t ws_size,
                              hipStream_t stream) {
    const float* x  = (const float*)d_in[0];
    const float* iw = (const float*)d_in[1];
    const float* th = (const float*)d_in[2];
    const float* ow = (const float*)d_in[3];
    float* out = (float*)d_out;
    const int batch = in_sizes[0] / NQ;
    hipLaunchKernelGGL(qnet_kernel, dim3(batch), dim3(TPB), 0, stream,
                       x, iw, th, ow, out);
}